// Round 1
// 254.632 us; speedup vs baseline: 1.0465x; 1.0465x over previous
//
#include <hip/hip_runtime.h>
#include <cstdint>
#include <cstddef>

// GraphSAGE 3-layer, N=100000 nodes, E=1600000 edges, dims 64->64->64->32.
// Transform-then-aggregate; padded CSR via 256-node super-buckets (2 kernels);
// weights pre-swizzled once into MFMA B-frag layout (merged into bin kernel);
// per-layer dual GEMMs (t=h@Wl, r=h@Wr+b, mfma_f32_16x16x32_bf16) LDS-free,
// barrier-free; t for layers 0/1 fp8 e4m3 (row = 64B = 1 line), t2 bf16.
// R13: CSR padded to 8-edge multiples with sentinel row N (zeroed in gemm) ->
//      gather loop is branch-free 8-unroll, colidx loads as int4; r bf16 for
//      layers 0/1 (joins fp8-noise-limited data; layer-2 r stays fp32).
// R4: LDS-atomic aggregation is 12x slower than CSR gather — don't revisit.
// R6: per-node scatter -> 64B-line write amplification, keep super-buckets.
// R7: 196-block bin_coarse latency-bound; 782 blocks.
// R10: gather+GEMM fusion halves occupancy, couples imbalance — keep split.
// R12: R11's "slow GEMM" was broken weight staging; fp8 gather is the win.

constexpr int SBW = 256;     // dst nodes per super-bucket
constexpr int LOGSBW = 8;
constexpr int CAPS = 4608;   // super capacity (unpadded); mean 4096, +8 sigma
constexpr int CAPSP = 5632;  // padded capacity; mean ~4992, +9 sigma, %8==0
constexpr int CHK = 2048;    // edges per bin block -> 782 blocks

typedef __attribute__((ext_vector_type(8))) short s16x8;
typedef __attribute__((ext_vector_type(4))) float f32x4;
typedef __attribute__((ext_vector_type(2))) float f32x2;

__device__ inline unsigned short f2bf(float f) {
  unsigned u = __builtin_bit_cast(unsigned, f);
  u += 0x7FFFu + ((u >> 16) & 1u);          // round-to-nearest-even
  return (unsigned short)(u >> 16);
}
__device__ inline float bf2f(unsigned short b) {
  unsigned u = ((unsigned)b) << 16;
  return __builtin_bit_cast(float, u);
}
__device__ inline unsigned char f2fp8(float f) {
  int p = __builtin_amdgcn_cvt_pk_fp8_f32(f, f, 0, false);
  return (unsigned char)(p & 0xFF);
}

// ------- pass 1: coarse bin into super-buckets + one-shot weight swizzle ---
// blocks [0, bbl): binning. blocks [bbl, bbl+40): weight swizzle into MFMA
// B-frag layout. Per layer 2*NTT tiles (Wl then Wr); per tile 2 planes
// (k<32, k>=32); per plane 64 lanes x 8 bf16: W[k=plane*32+q*8+j][col=c*16+m].
// Layer short offsets: L0=0, L1=8192, L2=16384. gemm fetch:
// frag = Wsw[off + (c*2+plane)*512 + lane*8 ..+8] (16B/lane, coalesced).

__global__ __launch_bounds__(256) void bin_stage(const int* __restrict__ src,
                                                 const int* __restrict__ dst,
                                                 int* __restrict__ bcur,
                                                 unsigned int* __restrict__ coarse,
                                                 int NSB, int E,
                                                 const float* __restrict__ Wl0,
                                                 const float* __restrict__ Wr0,
                                                 const float* __restrict__ Wl1,
                                                 const float* __restrict__ Wr1,
                                                 const float* __restrict__ Wl2,
                                                 const float* __restrict__ Wr2,
                                                 unsigned short* __restrict__ Wsw) {
  __shared__ int h[512];
  __shared__ unsigned ed[CHK];
  __shared__ short sb[CHK];
  const int tid = threadIdx.x;
  const int bbl = (E + CHK - 1) / CHK;
  if ((int)blockIdx.x >= bbl) {
    // ---- weight swizzle path ----
    int g = (blockIdx.x - bbl) * 256 + tid;    // u32 index
    if (g >= 10240) return;
    int s = g * 2;                             // short index (j even)
    int layer, off;
    if (s < 8192)       { layer = 0; off = 0; }
    else if (s < 16384) { layer = 1; off = 8192; }
    else                { layer = 2; off = 16384; }
    int t = s - off;
    int D = (layer == 2) ? 32 : 64;
    int NTT = D / 16;
    int tt = t >> 10;
    int rem = t & 1023;
    int plane = rem >> 9;
    int rem2 = rem & 511;
    int lane = rem2 >> 3;
    int j = rem2 & 7;
    int q = lane >> 4, m = lane & 15;
    int k = plane * 32 + q * 8 + j;
    const float* W;
    int c;
    if (tt < NTT) {
      c = tt;
      W = (layer == 0) ? Wl0 : (layer == 1) ? Wl1 : Wl2;
    } else {
      c = tt - NTT;
      W = (layer == 0) ? Wr0 : (layer == 1) ? Wr1 : Wr2;
    }
    int col = c * 16 + m;
    unsigned lo = f2bf(W[k * D + col]);
    unsigned hi = f2bf(W[(k + 1) * D + col]);
    *(unsigned*)&Wsw[s] = lo | (hi << 16);
    return;
  }
  // ---- binning path ----
  for (int i = tid; i < NSB; i += 256) h[i] = 0;
  __syncthreads();
  const int e0 = blockIdx.x * CHK;
  const int e1 = min(E, e0 + CHK);
  for (int e = e0 + tid; e < e1; e += 256) {
    int d = dst[e];
    int s = src[e];
    int b = d >> LOGSBW;
    ed[e - e0] = (unsigned)s | ((unsigned)(d & (SBW - 1)) << 17);
    sb[e - e0] = (short)b;
    atomicAdd(&h[b], 1);
  }
  __syncthreads();
  for (int i = tid; i < NSB; i += 256) {
    int c = h[i];
    h[i] = c ? (i * CAPS + atomicAdd(&bcur[i], c)) : 0;  // slot -> abs cursor
  }
  __syncthreads();
  const int n = e1 - e0;
  for (int k = tid; k < n; k += 256) {
    int b = sb[k];
    int pos = atomicAdd(&h[b], 1);
    if (pos < (b + 1) * CAPS)                 // overflow guard (never taken)
      coarse[pos] = ed[k];
  }
}

// ------- pass 2: per-super count/scan/sort -> PADDED CSR -------------------
// Per-node segment padded to a multiple of 8 with sentinel colidx=N (row N of
// every t buffer is zero). rowstart/segments are 32B-aligned -> int4 colidx
// loads in the gathers, no remainder loop, no per-edge bound check.

__global__ __launch_bounds__(256) void super_csr(const unsigned int* __restrict__ coarse,
                                                 const int* __restrict__ bcur,
                                                 int* __restrict__ rowstart,
                                                 int* __restrict__ degarr,
                                                 float* __restrict__ deg_inv,
                                                 int* __restrict__ colidx,
                                                 int N) {
  __shared__ int cnt[SBW];
  __shared__ int sc[SBW];
  __shared__ int cur[SBW];
  const int b = blockIdx.x;
  const int tid = threadIdx.x;
  cnt[tid] = 0;
  __syncthreads();
  const int ec = min(bcur[b], CAPS);
  const int baseC = b * CAPS;
  const int baseP = b * CAPSP;
  for (int e = tid; e < ec; e += 256)
    atomicAdd(&cnt[coarse[baseC + e] >> 17], 1);
  __syncthreads();
  int v = cnt[tid];
  int pc = (v + 7) & ~7;                      // padded count
  sc[tid] = pc;
  __syncthreads();
  for (int off = 1; off < SBW; off <<= 1) {
    int y = sc[tid];
    if (tid >= off) y += sc[tid - off];
    __syncthreads();
    sc[tid] = y;
    __syncthreads();
  }
  int pex = sc[tid] - pc;                     // exclusive padded prefix
  cur[tid] = pex;
  int gn = b * SBW + tid;
  if (gn < N) {
    rowstart[gn] = baseP + pex;
    degarr[gn] = pc;                          // padded extent for the gather
    deg_inv[gn] = 1.0f / (float)(v > 1 ? v : 1);
  }
  __syncthreads();
  for (int e = tid; e < ec; e += 256) {
    unsigned p = coarse[baseC + e];
    int dl = (int)(p >> 17);
    int s = (int)(p & 0x1FFFFu);
    int l = atomicAdd(&cur[dl], 1);
    if (l < CAPSP)                            // overflow guard (never taken)
      colidx[baseP + l] = s;
  }
  // sentinel padding (disjoint from scatter range, no sync needed)
  int pe = pex + pc;
  if (pe > CAPSP) pe = CAPSP;
  for (int l = pex + v; l < pe; ++l) colidx[baseP + l] = N;
}

// ------- layer-0 MFMA dual GEMM, fp32 input, LDS-free ----------------------
// C/D layout: col=lane&15, row=(lane>>4)*4+reg (m89-verified). t fp8, r bf16.

__global__ __launch_bounds__(256) void gemm0_mfma(const float* __restrict__ x,
                                                  const unsigned short* __restrict__ Wf,
                                                  const float* __restrict__ bias,
                                                  unsigned char* __restrict__ t_out,
                                                  unsigned short* __restrict__ r_out,
                                                  int N) {
  constexpr int DOUT = 64;
  constexpr int NTT = 4;
  const int tid = threadIdx.x;
  // zero sentinel row N of t (64B)
  if (blockIdx.x == 0 && tid < 16)
    ((unsigned*)t_out)[(size_t)N * 16 + tid] = 0u;
  const int wv = tid >> 6, lane = tid & 63;
  const int q = lane >> 4, m = lane & 15;
  const int row = blockIdx.x * 64 + wv * 16 + m;
  const int rowc = row < N ? row : N - 1;
  const float* xp = &x[(size_t)rowc * 64];
  float4 f0 = *(const float4*)&xp[q * 8];
  float4 f1 = *(const float4*)&xp[q * 8 + 4];
  float4 f2 = *(const float4*)&xp[32 + q * 8];
  float4 f3 = *(const float4*)&xp[32 + q * 8 + 4];
  s16x8 a0, a1;
  a0[0] = (short)f2bf(f0.x); a0[1] = (short)f2bf(f0.y);
  a0[2] = (short)f2bf(f0.z); a0[3] = (short)f2bf(f0.w);
  a0[4] = (short)f2bf(f1.x); a0[5] = (short)f2bf(f1.y);
  a0[6] = (short)f2bf(f1.z); a0[7] = (short)f2bf(f1.w);
  a1[0] = (short)f2bf(f2.x); a1[1] = (short)f2bf(f2.y);
  a1[2] = (short)f2bf(f2.z); a1[3] = (short)f2bf(f2.w);
  a1[4] = (short)f2bf(f3.x); a1[5] = (short)f2bf(f3.y);
  a1[6] = (short)f2bf(f3.z); a1[7] = (short)f2bf(f3.w);

  f32x4 acc[2 * NTT];
#pragma unroll
  for (int c = 0; c < 2 * NTT; ++c) acc[c] = (f32x4){0.f, 0.f, 0.f, 0.f};
#pragma unroll
  for (int c = 0; c < 2 * NTT; ++c) {
    s16x8 b0 = *(const s16x8*)&Wf[(c * 2 + 0) * 512 + lane * 8];
    s16x8 b1 = *(const s16x8*)&Wf[(c * 2 + 1) * 512 + lane * 8];
    acc[c] = __builtin_amdgcn_mfma_f32_16x16x32_bf16(a0, b0, acc[c], 0, 0, 0);
    acc[c] = __builtin_amdgcn_mfma_f32_16x16x32_bf16(a1, b1, acc[c], 0, 0, 0);
  }

  const int orow = blockIdx.x * 64 + wv * 16 + q * 4;
#pragma unroll
  for (int c = 0; c < NTT; ++c) {
#pragma unroll
    for (int i = 0; i < 4; ++i) {
      int r_ = orow + i;
      if (r_ < N) t_out[(size_t)r_ * DOUT + c * 16 + m] = f2fp8(acc[c][i]);
    }
  }
#pragma unroll
  for (int c = 0; c < NTT; ++c) {
    float bv = bias[c * 16 + m];
#pragma unroll
    for (int i = 0; i < 4; ++i) {
      int r_ = orow + i;
      if (r_ < N) r_out[(size_t)r_ * DOUT + c * 16 + m] = f2bf(acc[NTT + c][i] + bv);
    }
  }
}

// ------- mid/final MFMA dual GEMM, bf16 input, LDS-free --------------------
// TFP8: t out fp8 (layer 1) else bf16 (layer 2). RB16: r out bf16 else fp32.

template <int DOUT, bool TFP8, bool RB16>
__global__ __launch_bounds__(256) void gemm_mfma(const unsigned short* __restrict__ Hm,
                                                 const unsigned short* __restrict__ Wf,
                                                 const float* __restrict__ bias,
                                                 void* __restrict__ t_out,
                                                 void* __restrict__ r_out, int N) {
  constexpr int NTT = DOUT / 16;
  constexpr int ROWB = TFP8 ? DOUT : DOUT * 2;   // t row bytes (always 64 here)
  const int tid = threadIdx.x;
  if (blockIdx.x == 0 && tid < ROWB / 4)        // zero sentinel row N of t
    ((unsigned*)((char*)t_out + (size_t)N * ROWB))[tid] = 0u;
  const int wv = tid >> 6, lane = tid & 63;
  const int q = lane >> 4, m = lane & 15;
  const int row = blockIdx.x * 64 + wv * 16 + m;
  const int rowc = row < N ? row : N - 1;
  const s16x8 a0 = *(const s16x8*)&Hm[(size_t)rowc * 64 + q * 8];
  const s16x8 a1 = *(const s16x8*)&Hm[(size_t)rowc * 64 + 32 + q * 8];

  f32x4 acc[2 * NTT];
#pragma unroll
  for (int c = 0; c < 2 * NTT; ++c) acc[c] = (f32x4){0.f, 0.f, 0.f, 0.f};
#pragma unroll
  for (int c = 0; c < 2 * NTT; ++c) {
    s16x8 b0 = *(const s16x8*)&Wf[(c * 2 + 0) * 512 + lane * 8];
    s16x8 b1 = *(const s16x8*)&Wf[(c * 2 + 1) * 512 + lane * 8];
    acc[c] = __builtin_amdgcn_mfma_f32_16x16x32_bf16(a0, b0, acc[c], 0, 0, 0);
    acc[c] = __builtin_amdgcn_mfma_f32_16x16x32_bf16(a1, b1, acc[c], 0, 0, 0);
  }

  const int orow = blockIdx.x * 64 + wv * 16 + q * 4;
#pragma unroll
  for (int c = 0; c < NTT; ++c) {
#pragma unroll
    for (int i = 0; i < 4; ++i) {
      int r_ = orow + i;
      if (r_ < N) {
        if (TFP8)
          ((unsigned char*)t_out)[(size_t)r_ * DOUT + c * 16 + m] = f2fp8(acc[c][i]);
        else
          ((unsigned short*)t_out)[(size_t)r_ * DOUT + c * 16 + m] = f2bf(acc[c][i]);
      }
    }
  }
#pragma unroll
  for (int c = 0; c < NTT; ++c) {
    float bv = bias[c * 16 + m];
#pragma unroll
    for (int i = 0; i < 4; ++i) {
      int r_ = orow + i;
      if (r_ < N) {
        if (RB16)
          ((unsigned short*)r_out)[(size_t)r_ * DOUT + c * 16 + m] =
              f2bf(acc[NTT + c][i] + bv);
        else
          ((float*)r_out)[(size_t)r_ * DOUT + c * 16 + m] = acc[NTT + c][i] + bv;
      }
    }
  }
}

// ------- gather (fp8 t): h = bf16(elu(deg_inv * sum t[src] + r)) -----------
// 8 lanes/node, uint2/lane = 8 fp8 feats; row = 64B = 1 line. Segments padded
// to 8 -> branch-free 8-unroll, int4 colidx loads. r read as bf16.

__global__ __launch_bounds__(256) void gather_fp8(const uint2* __restrict__ t,
                                                  const unsigned short* __restrict__ r,
                                                  const float* __restrict__ deg_inv,
                                                  const int* __restrict__ rowstart,
                                                  const int* __restrict__ degarr,
                                                  const int* __restrict__ colidx,
                                                  unsigned short* __restrict__ Xout,
                                                  int N) {
  int node = blockIdx.x * 32 + (threadIdx.x >> 3);
  int lane = threadIdx.x & 7;
  if (node >= N) return;
  int b = rowstart[node];
  int e = b + degarr[node];                    // padded, multiple of 8
  float s[8];
#pragma unroll
  for (int k = 0; k < 8; ++k) s[k] = 0.f;
  for (int i = b; i < e; i += 8) {
    int4 c0 = *(const int4*)&colidx[i];
    int4 c1 = *(const int4*)&colidx[i + 4];
    uint2 v[8];
    v[0] = t[(size_t)c0.x * 8 + lane];
    v[1] = t[(size_t)c0.y * 8 + lane];
    v[2] = t[(size_t)c0.z * 8 + lane];
    v[3] = t[(size_t)c0.w * 8 + lane];
    v[4] = t[(size_t)c1.x * 8 + lane];
    v[5] = t[(size_t)c1.y * 8 + lane];
    v[6] = t[(size_t)c1.z * 8 + lane];
    v[7] = t[(size_t)c1.w * 8 + lane];
#pragma unroll
    for (int j = 0; j < 8; ++j) {
      f32x2 p0 = __builtin_amdgcn_cvt_pk_f32_fp8((int)v[j].x, false);
      f32x2 p1 = __builtin_amdgcn_cvt_pk_f32_fp8((int)v[j].x, true);
      f32x2 p2 = __builtin_amdgcn_cvt_pk_f32_fp8((int)v[j].y, false);
      f32x2 p3 = __builtin_amdgcn_cvt_pk_f32_fp8((int)v[j].y, true);
      s[0] += p0[0]; s[1] += p0[1]; s[2] += p1[0]; s[3] += p1[1];
      s[4] += p2[0]; s[5] += p2[1]; s[6] += p3[0]; s[7] += p3[1];
    }
  }
  float dv = deg_inv[node];
  const s16x8 rv = *(const s16x8*)&r[(size_t)node * 64 + lane * 8];
  float a[8];
#pragma unroll
  for (int k = 0; k < 8; ++k) a[k] = s[k] * dv + bf2f((unsigned short)rv[k]);
  s16x8 hv;
#pragma unroll
  for (int k = 0; k < 8; ++k) {
    float ak = a[k] > 0.f ? a[k] : (expf(a[k]) - 1.f);
    hv[k] = (short)f2bf(ak);
  }
  *(s16x8*)&Xout[(size_t)node * 64 + lane * 8] = hv;
}

// ------- final gather: out = deg_inv * sum t2[src] + r[dst], t2 bf16 -------

__global__ __launch_bounds__(256) void gather_out(const uint2* __restrict__ t,
                                                  const float* __restrict__ r,
                                                  const float* __restrict__ deg_inv,
                                                  const int* __restrict__ rowstart,
                                                  const int* __restrict__ degarr,
                                                  const int* __restrict__ colidx,
                                                  float* __restrict__ out, int N) {
  constexpr int L = 8;                 // uint2 lanes per node
  int node = blockIdx.x * 32 + threadIdx.x / L;
  int lane = threadIdx.x & (L - 1);
  if (node >= N) return;
  int b = rowstart[node];
  int e = b + degarr[node];            // padded, multiple of 8
  float s0 = 0.f, s1 = 0.f, s2 = 0.f, s3 = 0.f;
  for (int i = b; i < e; i += 8) {
    int4 c0 = *(const int4*)&colidx[i];
    int4 c1 = *(const int4*)&colidx[i + 4];
    uint2 v[8];
    v[0] = t[(size_t)c0.x * L + lane];
    v[1] = t[(size_t)c0.y * L + lane];
    v[2] = t[(size_t)c0.z * L + lane];
    v[3] = t[(size_t)c0.w * L + lane];
    v[4] = t[(size_t)c1.x * L + lane];
    v[5] = t[(size_t)c1.y * L + lane];
    v[6] = t[(size_t)c1.z * L + lane];
    v[7] = t[(size_t)c1.w * L + lane];
#pragma unroll
    for (int j = 0; j < 8; ++j) {
      s0 += bf2f((unsigned short)(v[j].x & 0xFFFFu));
      s1 += bf2f((unsigned short)(v[j].x >> 16));
      s2 += bf2f((unsigned short)(v[j].y & 0xFFFFu));
      s3 += bf2f((unsigned short)(v[j].y >> 16));
    }
  }
  float dv = deg_inv[node];
  float4 rv = *(const float4*)&r[(size_t)node * 32 + 4 * lane];
  *(float4*)&out[(size_t)node * 32 + 4 * lane] =
      make_float4(s0 * dv + rv.x, s1 * dv + rv.y, s2 * dv + rv.z, s3 * dv + rv.w);
}

// ---------------- launch ----------------

extern "C" void kernel_launch(void* const* d_in, const int* in_sizes, int n_in,
                              void* d_out, int out_size, void* d_ws, size_t ws_size,
                              hipStream_t stream) {
  const float* x   = (const float*)d_in[0];
  const int*   ei  = (const int*)d_in[1];
  const float* Wl0 = (const float*)d_in[2];
  const float* Wr0 = (const float*)d_in[3];
  const float* b0  = (const float*)d_in[4];
  const float* Wl1 = (const float*)d_in[5];
  const float* Wr1 = (const float*)d_in[6];
  const float* b1  = (const float*)d_in[7];
  const float* Wl2 = (const float*)d_in[8];
  const float* Wr2 = (const float*)d_in[9];
  const float* b2  = (const float*)d_in[10];
  float* out = (float*)d_out;

  const int N = in_sizes[0] / 64;   // 100000
  const int E = in_sizes[1] / 2;    // 1600000
  const int* srcv = ei;
  const int* dstv = ei + E;
  const int NSB = (N + SBW - 1) >> LOGSBW;   // 391

  auto al = [](size_t v) { return (v + 255) & ~(size_t)255; };
  char* w = (char*)d_ws;
  size_t oBcur = 0;
  size_t oRow  = oBcur + al(4 * (size_t)NSB);
  size_t oDeg  = oRow + al(4 * (size_t)N);
  size_t oDinv = oDeg + al(4 * (size_t)N);
  size_t oWsw  = oDinv + al(4 * (size_t)N);
  size_t oBin  = oWsw + al(2 * 20480);
  size_t oCol  = oBin + al(4 * (size_t)NSB * CAPS);
  size_t oP8   = oCol + al(4 * (size_t)NSB * CAPSP);
  size_t oP16  = oP8 + al((size_t)(N + 1) * 64);   // fp8 t0/t1 (+sentinel row)
  size_t oX    = oP16 + al((size_t)(N + 1) * 64);  // bf16 t2 (+sentinel row)
  size_t oR    = oX + al(2 * (size_t)N * 64);      // bf16 h buffer
  // total = oR + 2*N*64  (~55 MiB); r buffer: bf16 [N][64] or fp32 [N][32]

  int*            bcur     = (int*)(w + oBcur);
  int*            rowstart = (int*)(w + oRow);
  int*            degarr   = (int*)(w + oDeg);
  float*          deg_inv  = (float*)(w + oDinv);
  unsigned short* Wsw      = (unsigned short*)(w + oWsw); // swizzled weights
  unsigned*       coarse   = (unsigned*)(w + oBin);
  int*            colidx   = (int*)(w + oCol);
  unsigned char*  P8       = (unsigned char*)(w + oP8);   // fp8 t0/t1
  unsigned short* P16      = (unsigned short*)(w + oP16); // bf16 t2
  unsigned short* X        = (unsigned short*)(w + oX);   // bf16 h
  unsigned short* Rb       = (unsigned short*)(w + oR);   // bf16 r (L0/L1)
  float*          Rf       = (float*)(w + oR);            // fp32 r (L2)

  hipMemsetAsync(bcur, 0, (size_t)NSB * 4, stream);

  int bbl = (E + CHK - 1) / CHK;   // 782
  bin_stage<<<bbl + 40, 256, 0, stream>>>(srcv, dstv, bcur, coarse, NSB, E,
                                          Wl0, Wr0, Wl1, Wr1, Wl2, Wr2, Wsw);
  super_csr<<<NSB, 256, 0, stream>>>(coarse, bcur, rowstart, degarr, deg_inv, colidx, N);

  int gb = (N + 63) / 64;          // 1563
  int ggb = (N + 31) / 32;         // 3125
  // layer 0: fp32 x -> t0 (fp8 P8), r0 (bf16 Rb)
  gemm0_mfma<<<gb, 256, 0, stream>>>(x, Wsw, b0, P8, Rb, N);
  gather_fp8<<<ggb, 256, 0, stream>>>((const uint2*)P8, Rb, deg_inv, rowstart,
                                      degarr, colidx, X, N);
  // layer 1: X -> t1 (fp8 P8), r1 (bf16 Rb)
  gemm_mfma<64, true, true><<<gb, 256, 0, stream>>>(X, Wsw + 8192, b1, P8, Rb, N);
  gather_fp8<<<ggb, 256, 0, stream>>>((const uint2*)P8, Rb, deg_inv, rowstart,
                                      degarr, colidx, X, N);
  // layer 2: X -> t2 (bf16 P16), r2 (fp32 Rf, [N][32])
  gemm_mfma<32, false, false><<<gb, 256, 0, stream>>>(X, Wsw + 16384, b2, P16, Rf, N);
  gather_out<<<ggb, 256, 0, stream>>>((const uint2*)P16, Rf, deg_inv, rowstart,
                                      degarr, colidx, out, N);
}

// Round 2
// 242.686 us; speedup vs baseline: 1.0981x; 1.0492x over previous
//
#include <hip/hip_runtime.h>
#include <cstdint>
#include <cstddef>

// GraphSAGE 3-layer, N=100000 nodes, E=1600000 edges, dims 64->64->64->32.
// Transform-then-aggregate; padded CSR via 256-node super-buckets;
// weights pre-swizzled once into MFMA B-frag layout (init_ws kernel);
// per-layer dual GEMMs (t=h@Wl, r=h@Wr+b, mfma_f32_16x16x32_bf16) LDS-free,
// barrier-free; t for layers 0/1 fp8 e4m3 (row = 64B = 1 line), t2 bf16;
// r bf16 for layers 0/1, fp32 for layer 2.
// R14: super_csr+gemm0 merged (independent; CSR latency hides under GEMM BW);
//      init_ws replaces memset+swizzle (8 dispatches); CSR pad 8 -> 4
//      (avg padded deg 19.8 -> 18.0, -9% gather bytes; 4-edge tail step).
// R13: pad-8 sentinel CSR (branch-free gather); r bf16 L0/L1. -12us, traffic
//      model matched; "divergence" component did NOT -> gathers are BW-bound.
// R4: LDS-atomic aggregation is 12x slower than CSR gather — don't revisit.
// R6: per-node scatter -> 64B-line write amplification, keep super-buckets.
// R10: gather+GEMM fusion halves occupancy, couples imbalance — keep split.
// R12: R11's "slow GEMM" was broken weight staging; fp8 gather is the win.

constexpr int SBW = 256;     // dst nodes per super-bucket
constexpr int LOGSBW = 8;
constexpr int CAPS = 4608;   // super capacity (unpadded); mean 4096, +8 sigma
constexpr int CAPSP = 5632;  // padded capacity; mean ~4608 (pad-4), %16==0
constexpr int CHK = 2048;    // edges per bin block -> 782 blocks

typedef __attribute__((ext_vector_type(8))) short s16x8;
typedef __attribute__((ext_vector_type(4))) float f32x4;
typedef __attribute__((ext_vector_type(2))) float f32x2;

__device__ inline unsigned short f2bf(float f) {
  unsigned u = __builtin_bit_cast(unsigned, f);
  u += 0x7FFFu + ((u >> 16) & 1u);          // round-to-nearest-even
  return (unsigned short)(u >> 16);
}
__device__ inline float bf2f(unsigned short b) {
  unsigned u = ((unsigned)b) << 16;
  return __builtin_bit_cast(float, u);
}
__device__ inline unsigned char f2fp8(float f) {
  int p = __builtin_amdgcn_cvt_pk_fp8_f32(f, f, 0, false);
  return (unsigned char)(p & 0xFF);
}

// ------- init: zero bcur (block 0) + weight swizzle (blocks 1..40) ---------
// Swizzle: per layer 2*NTT tiles (Wl then Wr); per tile 2 planes (k<32,
// k>=32); per plane 64 lanes x 8 bf16: W[k=plane*32+q*8+j][col=c*16+m].
// Layer short offsets: L0=0, L1=8192, L2=16384. gemm fetch:
// frag = Wsw[off + (c*2+plane)*512 + lane*8 ..+8] (16B/lane, coalesced).

__global__ __launch_bounds__(256) void init_ws(int* __restrict__ bcur, int NSB,
                                               const float* __restrict__ Wl0,
                                               const float* __restrict__ Wr0,
                                               const float* __restrict__ Wl1,
                                               const float* __restrict__ Wr1,
                                               const float* __restrict__ Wl2,
                                               const float* __restrict__ Wr2,
                                               unsigned short* __restrict__ Wsw) {
  const int tid = threadIdx.x;
  if (blockIdx.x == 0) {
    for (int i = tid; i < NSB; i += 256) bcur[i] = 0;
    return;
  }
  int g = (blockIdx.x - 1) * 256 + tid;        // u32 index
  if (g >= 10240) return;
  int s = g * 2;                               // short index (j even)
  int layer, off;
  if (s < 8192)       { layer = 0; off = 0; }
  else if (s < 16384) { layer = 1; off = 8192; }
  else                { layer = 2; off = 16384; }
  int t = s - off;
  int D = (layer == 2) ? 32 : 64;
  int NTT = D / 16;
  int tt = t >> 10;
  int rem = t & 1023;
  int plane = rem >> 9;
  int rem2 = rem & 511;
  int lane = rem2 >> 3;
  int j = rem2 & 7;
  int q = lane >> 4, m = lane & 15;
  int k = plane * 32 + q * 8 + j;
  const float* W;
  int c;
  if (tt < NTT) {
    c = tt;
    W = (layer == 0) ? Wl0 : (layer == 1) ? Wl1 : Wl2;
  } else {
    c = tt - NTT;
    W = (layer == 0) ? Wr0 : (layer == 1) ? Wr1 : Wr2;
  }
  int col = c * 16 + m;
  unsigned lo = f2bf(W[k * D + col]);
  unsigned hi = f2bf(W[(k + 1) * D + col]);
  *(unsigned*)&Wsw[s] = lo | (hi << 16);
}

// ------- pass 1: coarse bin into 256-node super-buckets --------------------

__global__ __launch_bounds__(256) void bin_coarse(const int* __restrict__ src,
                                                  const int* __restrict__ dst,
                                                  int* __restrict__ bcur,
                                                  unsigned int* __restrict__ coarse,
                                                  int NSB, int E) {
  __shared__ int h[512];
  __shared__ unsigned ed[CHK];
  __shared__ short sb[CHK];
  const int tid = threadIdx.x;
  for (int i = tid; i < NSB; i += 256) h[i] = 0;
  __syncthreads();
  const int e0 = blockIdx.x * CHK;
  const int e1 = min(E, e0 + CHK);
  for (int e = e0 + tid; e < e1; e += 256) {
    int d = dst[e];
    int s = src[e];
    int b = d >> LOGSBW;
    ed[e - e0] = (unsigned)s | ((unsigned)(d & (SBW - 1)) << 17);
    sb[e - e0] = (short)b;
    atomicAdd(&h[b], 1);
  }
  __syncthreads();
  for (int i = tid; i < NSB; i += 256) {
    int c = h[i];
    h[i] = c ? (i * CAPS + atomicAdd(&bcur[i], c)) : 0;  // slot -> abs cursor
  }
  __syncthreads();
  const int n = e1 - e0;
  for (int k = tid; k < n; k += 256) {
    int b = sb[k];
    int pos = atomicAdd(&h[b], 1);
    if (pos < (b + 1) * CAPS)                 // overflow guard (never taken)
      coarse[pos] = ed[k];
  }
}

// ------- pass 2: per-super count/scan/sort -> PADDED CSR, merged with -----
// ------- layer-0 dual GEMM (independent work, fills the idle CUs) ---------
// CSR: blocks [0,NSB). Segments padded to x4 with sentinel colidx=N (row N
// of t buffers is zero) -> branch-free gather main loop + one 4-edge tail,
// int4 colidx loads (CAPSP%16==0, prefix sums stay x4).
// GEMM0: blocks [NSB, NSB+gb): fp32 x -> t0 fp8 + r0 bf16.
// C/D layout: col=lane&15, row=(lane>>4)*4+reg (m89-verified).

__global__ __launch_bounds__(256) void csr_gemm0(const unsigned int* __restrict__ coarse,
                                                 const int* __restrict__ bcur,
                                                 int* __restrict__ rowstart,
                                                 int* __restrict__ degarr,
                                                 float* __restrict__ deg_inv,
                                                 int* __restrict__ colidx,
                                                 const float* __restrict__ x,
                                                 const unsigned short* __restrict__ Wf,
                                                 const float* __restrict__ bias,
                                                 unsigned char* __restrict__ t_out,
                                                 unsigned short* __restrict__ r_out,
                                                 int N, int NSB) {
  __shared__ int cnt[SBW];
  __shared__ int sc[SBW];
  __shared__ int cur[SBW];
  const int tid = threadIdx.x;
  if ((int)blockIdx.x < NSB) {
    // ---------------- CSR path ----------------
    const int b = blockIdx.x;
    cnt[tid] = 0;
    __syncthreads();
    const int ec = min(bcur[b], CAPS);
    const int baseC = b * CAPS;
    const int baseP = b * CAPSP;
    for (int e = tid; e < ec; e += 256)
      atomicAdd(&cnt[coarse[baseC + e] >> 17], 1);
    __syncthreads();
    int v = cnt[tid];
    int pc = (v + 3) & ~3;                      // padded count (x4)
    sc[tid] = pc;
    __syncthreads();
    for (int off = 1; off < SBW; off <<= 1) {
      int y = sc[tid];
      if (tid >= off) y += sc[tid - off];
      __syncthreads();
      sc[tid] = y;
      __syncthreads();
    }
    int pex = sc[tid] - pc;                     // exclusive padded prefix
    cur[tid] = pex;
    int gn = b * SBW + tid;
    if (gn < N) {
      rowstart[gn] = baseP + pex;
      degarr[gn] = pc;                          // padded extent for the gather
      deg_inv[gn] = 1.0f / (float)(v > 1 ? v : 1);
    }
    __syncthreads();
    for (int e = tid; e < ec; e += 256) {
      unsigned p = coarse[baseC + e];
      int dl = (int)(p >> 17);
      int s = (int)(p & 0x1FFFFu);
      int l = atomicAdd(&cur[dl], 1);
      if (l < CAPSP)                            // overflow guard (never taken)
        colidx[baseP + l] = s;
    }
    // sentinel padding (disjoint from scatter range, no sync needed)
    int pe = pex + pc;
    if (pe > CAPSP) pe = CAPSP;
    for (int l = pex + v; l < pe; ++l) colidx[baseP + l] = N;
    return;
  }
  // ---------------- GEMM0 path ----------------
  constexpr int DOUT = 64;
  constexpr int NTT = 4;
  const int gbid = blockIdx.x - NSB;
  if (gbid == 0 && tid < 16)                   // zero sentinel row N of t
    ((unsigned*)t_out)[(size_t)N * 16 + tid] = 0u;
  const int wv = tid >> 6, lane = tid & 63;
  const int q = lane >> 4, m = lane & 15;
  const int row = gbid * 64 + wv * 16 + m;
  const int rowc = row < N ? row : N - 1;
  const float* xp = &x[(size_t)rowc * 64];
  float4 f0 = *(const float4*)&xp[q * 8];
  float4 f1 = *(const float4*)&xp[q * 8 + 4];
  float4 f2 = *(const float4*)&xp[32 + q * 8];
  float4 f3 = *(const float4*)&xp[32 + q * 8 + 4];
  s16x8 a0, a1;
  a0[0] = (short)f2bf(f0.x); a0[1] = (short)f2bf(f0.y);
  a0[2] = (short)f2bf(f0.z); a0[3] = (short)f2bf(f0.w);
  a0[4] = (short)f2bf(f1.x); a0[5] = (short)f2bf(f1.y);
  a0[6] = (short)f2bf(f1.z); a0[7] = (short)f2bf(f1.w);
  a1[0] = (short)f2bf(f2.x); a1[1] = (short)f2bf(f2.y);
  a1[2] = (short)f2bf(f2.z); a1[3] = (short)f2bf(f2.w);
  a1[4] = (short)f2bf(f3.x); a1[5] = (short)f2bf(f3.y);
  a1[6] = (short)f2bf(f3.z); a1[7] = (short)f2bf(f3.w);

  f32x4 acc[2 * NTT];
#pragma unroll
  for (int c = 0; c < 2 * NTT; ++c) acc[c] = (f32x4){0.f, 0.f, 0.f, 0.f};
#pragma unroll
  for (int c = 0; c < 2 * NTT; ++c) {
    s16x8 b0 = *(const s16x8*)&Wf[(c * 2 + 0) * 512 + lane * 8];
    s16x8 b1 = *(const s16x8*)&Wf[(c * 2 + 1) * 512 + lane * 8];
    acc[c] = __builtin_amdgcn_mfma_f32_16x16x32_bf16(a0, b0, acc[c], 0, 0, 0);
    acc[c] = __builtin_amdgcn_mfma_f32_16x16x32_bf16(a1, b1, acc[c], 0, 0, 0);
  }

  const int orow = gbid * 64 + wv * 16 + q * 4;
#pragma unroll
  for (int c = 0; c < NTT; ++c) {
#pragma unroll
    for (int i = 0; i < 4; ++i) {
      int r_ = orow + i;
      if (r_ < N) t_out[(size_t)r_ * DOUT + c * 16 + m] = f2fp8(acc[c][i]);
    }
  }
#pragma unroll
  for (int c = 0; c < NTT; ++c) {
    float bv = bias[c * 16 + m];
#pragma unroll
    for (int i = 0; i < 4; ++i) {
      int r_ = orow + i;
      if (r_ < N) r_out[(size_t)r_ * DOUT + c * 16 + m] = f2bf(acc[NTT + c][i] + bv);
    }
  }
}

// ------- mid/final MFMA dual GEMM, bf16 input, LDS-free --------------------
// TFP8: t out fp8 (layer 1) else bf16 (layer 2). RB16: r out bf16 else fp32.

template <int DOUT, bool TFP8, bool RB16>
__global__ __launch_bounds__(256) void gemm_mfma(const unsigned short* __restrict__ Hm,
                                                 const unsigned short* __restrict__ Wf,
                                                 const float* __restrict__ bias,
                                                 void* __restrict__ t_out,
                                                 void* __restrict__ r_out, int N) {
  constexpr int NTT = DOUT / 16;
  constexpr int ROWB = TFP8 ? DOUT : DOUT * 2;   // t row bytes (always 64 here)
  const int tid = threadIdx.x;
  if (blockIdx.x == 0 && tid < ROWB / 4)        // zero sentinel row N of t
    ((unsigned*)((char*)t_out + (size_t)N * ROWB))[tid] = 0u;
  const int wv = tid >> 6, lane = tid & 63;
  const int q = lane >> 4, m = lane & 15;
  const int row = blockIdx.x * 64 + wv * 16 + m;
  const int rowc = row < N ? row : N - 1;
  const s16x8 a0 = *(const s16x8*)&Hm[(size_t)rowc * 64 + q * 8];
  const s16x8 a1 = *(const s16x8*)&Hm[(size_t)rowc * 64 + 32 + q * 8];

  f32x4 acc[2 * NTT];
#pragma unroll
  for (int c = 0; c < 2 * NTT; ++c) acc[c] = (f32x4){0.f, 0.f, 0.f, 0.f};
#pragma unroll
  for (int c = 0; c < 2 * NTT; ++c) {
    s16x8 b0 = *(const s16x8*)&Wf[(c * 2 + 0) * 512 + lane * 8];
    s16x8 b1 = *(const s16x8*)&Wf[(c * 2 + 1) * 512 + lane * 8];
    acc[c] = __builtin_amdgcn_mfma_f32_16x16x32_bf16(a0, b0, acc[c], 0, 0, 0);
    acc[c] = __builtin_amdgcn_mfma_f32_16x16x32_bf16(a1, b1, acc[c], 0, 0, 0);
  }

  const int orow = blockIdx.x * 64 + wv * 16 + q * 4;
#pragma unroll
  for (int c = 0; c < NTT; ++c) {
#pragma unroll
    for (int i = 0; i < 4; ++i) {
      int r_ = orow + i;
      if (r_ < N) {
        if (TFP8)
          ((unsigned char*)t_out)[(size_t)r_ * DOUT + c * 16 + m] = f2fp8(acc[c][i]);
        else
          ((unsigned short*)t_out)[(size_t)r_ * DOUT + c * 16 + m] = f2bf(acc[c][i]);
      }
    }
  }
#pragma unroll
  for (int c = 0; c < NTT; ++c) {
    float bv = bias[c * 16 + m];
#pragma unroll
    for (int i = 0; i < 4; ++i) {
      int r_ = orow + i;
      if (r_ < N) {
        if (RB16)
          ((unsigned short*)r_out)[(size_t)r_ * DOUT + c * 16 + m] =
              f2bf(acc[NTT + c][i] + bv);
        else
          ((float*)r_out)[(size_t)r_ * DOUT + c * 16 + m] = acc[NTT + c][i] + bv;
      }
    }
  }
}

// ------- gather (fp8 t): h = bf16(elu(deg_inv * sum t[src] + r)) -----------
// 8 lanes/node, uint2/lane = 8 fp8 feats; row = 64B = 1 line. Segments padded
// to x4 -> 8-unroll main loop + one 4-edge tail, int4 colidx loads, no
// per-edge guards. r read as bf16.

__global__ __launch_bounds__(256) void gather_fp8(const uint2* __restrict__ t,
                                                  const unsigned short* __restrict__ r,
                                                  const float* __restrict__ deg_inv,
                                                  const int* __restrict__ rowstart,
                                                  const int* __restrict__ degarr,
                                                  const int* __restrict__ colidx,
                                                  unsigned short* __restrict__ Xout,
                                                  int N) {
  int node = blockIdx.x * 32 + (threadIdx.x >> 3);
  int lane = threadIdx.x & 7;
  if (node >= N) return;
  int b = rowstart[node];
  int e = b + degarr[node];                    // padded, multiple of 4
  float s[8];
#pragma unroll
  for (int k = 0; k < 8; ++k) s[k] = 0.f;
  int i = b;
  for (; i + 8 <= e; i += 8) {
    int4 c0 = *(const int4*)&colidx[i];
    int4 c1 = *(const int4*)&colidx[i + 4];
    uint2 v[8];
    v[0] = t[(size_t)c0.x * 8 + lane];
    v[1] = t[(size_t)c0.y * 8 + lane];
    v[2] = t[(size_t)c0.z * 8 + lane];
    v[3] = t[(size_t)c0.w * 8 + lane];
    v[4] = t[(size_t)c1.x * 8 + lane];
    v[5] = t[(size_t)c1.y * 8 + lane];
    v[6] = t[(size_t)c1.z * 8 + lane];
    v[7] = t[(size_t)c1.w * 8 + lane];
#pragma unroll
    for (int j = 0; j < 8; ++j) {
      f32x2 p0 = __builtin_amdgcn_cvt_pk_f32_fp8((int)v[j].x, false);
      f32x2 p1 = __builtin_amdgcn_cvt_pk_f32_fp8((int)v[j].x, true);
      f32x2 p2 = __builtin_amdgcn_cvt_pk_f32_fp8((int)v[j].y, false);
      f32x2 p3 = __builtin_amdgcn_cvt_pk_f32_fp8((int)v[j].y, true);
      s[0] += p0[0]; s[1] += p0[1]; s[2] += p1[0]; s[3] += p1[1];
      s[4] += p2[0]; s[5] += p2[1]; s[6] += p3[0]; s[7] += p3[1];
    }
  }
  if (i < e) {                                 // exactly 4 remain
    int4 c0 = *(const int4*)&colidx[i];
    uint2 v[4];
    v[0] = t[(size_t)c0.x * 8 + lane];
    v[1] = t[(size_t)c0.y * 8 + lane];
    v[2] = t[(size_t)c0.z * 8 + lane];
    v[3] = t[(size_t)c0.w * 8 + lane];
#pragma unroll
    for (int j = 0; j < 4; ++j) {
      f32x2 p0 = __builtin_amdgcn_cvt_pk_f32_fp8((int)v[j].x, false);
      f32x2 p1 = __builtin_amdgcn_cvt_pk_f32_fp8((int)v[j].x, true);
      f32x2 p2 = __builtin_amdgcn_cvt_pk_f32_fp8((int)v[j].y, false);
      f32x2 p3 = __builtin_amdgcn_cvt_pk_f32_fp8((int)v[j].y, true);
      s[0] += p0[0]; s[1] += p0[1]; s[2] += p1[0]; s[3] += p1[1];
      s[4] += p2[0]; s[5] += p2[1]; s[6] += p3[0]; s[7] += p3[1];
    }
  }
  float dv = deg_inv[node];
  const s16x8 rv = *(const s16x8*)&r[(size_t)node * 64 + lane * 8];
  float a[8];
#pragma unroll
  for (int k = 0; k < 8; ++k) a[k] = s[k] * dv + bf2f((unsigned short)rv[k]);
  s16x8 hv;
#pragma unroll
  for (int k = 0; k < 8; ++k) {
    float ak = a[k] > 0.f ? a[k] : (expf(a[k]) - 1.f);
    hv[k] = (short)f2bf(ak);
  }
  *(s16x8*)&Xout[(size_t)node * 64 + lane * 8] = hv;
}

// ------- final gather: out = deg_inv * sum t2[src] + r[dst], t2 bf16 -------

__global__ __launch_bounds__(256) void gather_out(const uint2* __restrict__ t,
                                                  const float* __restrict__ r,
                                                  const float* __restrict__ deg_inv,
                                                  const int* __restrict__ rowstart,
                                                  const int* __restrict__ degarr,
                                                  const int* __restrict__ colidx,
                                                  float* __restrict__ out, int N) {
  constexpr int L = 8;                 // uint2 lanes per node
  int node = blockIdx.x * 32 + threadIdx.x / L;
  int lane = threadIdx.x & (L - 1);
  if (node >= N) return;
  int b = rowstart[node];
  int e = b + degarr[node];            // padded, multiple of 4
  float s0 = 0.f, s1 = 0.f, s2 = 0.f, s3 = 0.f;
  int i = b;
  for (; i + 8 <= e; i += 8) {
    int4 c0 = *(const int4*)&colidx[i];
    int4 c1 = *(const int4*)&colidx[i + 4];
    uint2 v[8];
    v[0] = t[(size_t)c0.x * L + lane];
    v[1] = t[(size_t)c0.y * L + lane];
    v[2] = t[(size_t)c0.z * L + lane];
    v[3] = t[(size_t)c0.w * L + lane];
    v[4] = t[(size_t)c1.x * L + lane];
    v[5] = t[(size_t)c1.y * L + lane];
    v[6] = t[(size_t)c1.z * L + lane];
    v[7] = t[(size_t)c1.w * L + lane];
#pragma unroll
    for (int j = 0; j < 8; ++j) {
      s0 += bf2f((unsigned short)(v[j].x & 0xFFFFu));
      s1 += bf2f((unsigned short)(v[j].x >> 16));
      s2 += bf2f((unsigned short)(v[j].y & 0xFFFFu));
      s3 += bf2f((unsigned short)(v[j].y >> 16));
    }
  }
  if (i < e) {                          // exactly 4 remain
    int4 c0 = *(const int4*)&colidx[i];
    uint2 v[4];
    v[0] = t[(size_t)c0.x * L + lane];
    v[1] = t[(size_t)c0.y * L + lane];
    v[2] = t[(size_t)c0.z * L + lane];
    v[3] = t[(size_t)c0.w * L + lane];
#pragma unroll
    for (int j = 0; j < 4; ++j) {
      s0 += bf2f((unsigned short)(v[j].x & 0xFFFFu));
      s1 += bf2f((unsigned short)(v[j].x >> 16));
      s2 += bf2f((unsigned short)(v[j].y & 0xFFFFu));
      s3 += bf2f((unsigned short)(v[j].y >> 16));
    }
  }
  float dv = deg_inv[node];
  float4 rv = *(const float4*)&r[(size_t)node * 32 + 4 * lane];
  *(float4*)&out[(size_t)node * 32 + 4 * lane] =
      make_float4(s0 * dv + rv.x, s1 * dv + rv.y, s2 * dv + rv.z, s3 * dv + rv.w);
}

// ---------------- launch ----------------

extern "C" void kernel_launch(void* const* d_in, const int* in_sizes, int n_in,
                              void* d_out, int out_size, void* d_ws, size_t ws_size,
                              hipStream_t stream) {
  const float* x   = (const float*)d_in[0];
  const int*   ei  = (const int*)d_in[1];
  const float* Wl0 = (const float*)d_in[2];
  const float* Wr0 = (const float*)d_in[3];
  const float* b0  = (const float*)d_in[4];
  const float* Wl1 = (const float*)d_in[5];
  const float* Wr1 = (const float*)d_in[6];
  const float* b1  = (const float*)d_in[7];
  const float* Wl2 = (const float*)d_in[8];
  const float* Wr2 = (const float*)d_in[9];
  const float* b2  = (const float*)d_in[10];
  float* out = (float*)d_out;

  const int N = in_sizes[0] / 64;   // 100000
  const int E = in_sizes[1] / 2;    // 1600000
  const int* srcv = ei;
  const int* dstv = ei + E;
  const int NSB = (N + SBW - 1) >> LOGSBW;   // 391

  auto al = [](size_t v) { return (v + 255) & ~(size_t)255; };
  char* w = (char*)d_ws;
  size_t oBcur = 0;
  size_t oRow  = oBcur + al(4 * (size_t)NSB);
  size_t oDeg  = oRow + al(4 * (size_t)N);
  size_t oDinv = oDeg + al(4 * (size_t)N);
  size_t oWsw  = oDinv + al(4 * (size_t)N);
  size_t oBin  = oWsw + al(2 * 20480);
  size_t oCol  = oBin + al(4 * (size_t)NSB * CAPS);
  size_t oP8   = oCol + al(4 * (size_t)NSB * CAPSP);
  size_t oP16  = oP8 + al((size_t)(N + 1) * 64);   // fp8 t0/t1 (+sentinel row)
  size_t oX    = oP16 + al((size_t)(N + 1) * 64);  // bf16 t2 (+sentinel row)
  size_t oR    = oX + al(2 * (size_t)N * 64);      // bf16 h buffer
  // total = oR + 2*N*64  (~55 MiB); r buffer: bf16 [N][64] or fp32 [N][32]

  int*            bcur     = (int*)(w + oBcur);
  int*            rowstart = (int*)(w + oRow);
  int*            degarr   = (int*)(w + oDeg);
  float*          deg_inv  = (float*)(w + oDinv);
  unsigned short* Wsw      = (unsigned short*)(w + oWsw); // swizzled weights
  unsigned*       coarse   = (unsigned*)(w + oBin);
  int*            colidx   = (int*)(w + oCol);
  unsigned char*  P8       = (unsigned char*)(w + oP8);   // fp8 t0/t1
  unsigned short* P16      = (unsigned short*)(w + oP16); // bf16 t2
  unsigned short* X        = (unsigned short*)(w + oX);   // bf16 h
  unsigned short* Rb       = (unsigned short*)(w + oR);   // bf16 r (L0/L1)
  float*          Rf       = (float*)(w + oR);            // fp32 r (L2)

  int bbl = (E + CHK - 1) / CHK;   // 782
  int gb = (N + 63) / 64;          // 1563
  int ggb = (N + 31) / 32;         // 3125

  init_ws<<<41, 256, 0, stream>>>(bcur, NSB, Wl0, Wr0, Wl1, Wr1, Wl2, Wr2, Wsw);
  bin_coarse<<<bbl, 256, 0, stream>>>(srcv, dstv, bcur, coarse, NSB, E);
  // CSR build (blocks [0,NSB)) overlapped with layer-0 GEMM (blocks [NSB,..))
  csr_gemm0<<<NSB + gb, 256, 0, stream>>>(coarse, bcur, rowstart, degarr,
                                          deg_inv, colidx, x, Wsw, b0, P8, Rb,
                                          N, NSB);
  gather_fp8<<<ggb, 256, 0, stream>>>((const uint2*)P8, Rb, deg_inv, rowstart,
                                      degarr, colidx, X, N);
  // layer 1: X -> t1 (fp8 P8), r1 (bf16 Rb)
  gemm_mfma<64, true, true><<<gb, 256, 0, stream>>>(X, Wsw + 8192, b1, P8, Rb, N);
  gather_fp8<<<ggb, 256, 0, stream>>>((const uint2*)P8, Rb, deg_inv, rowstart,
                                      degarr, colidx, X, N);
  // layer 2: X -> t2 (bf16 P16), r2 (fp32 Rf, [N][32])
  gemm_mfma<32, false, false><<<gb, 256, 0, stream>>>(X, Wsw + 16384, b2, P16, Rf, N);
  gather_out<<<ggb, 256, 0, stream>>>((const uint2*)P16, Rf, deg_inv, rowstart,
                                      degarr, colidx, out, N);
}